// Round 2
// baseline (318.017 us; speedup 1.0000x reference)
//
#include <hip/hip_runtime.h>

// GLRU associative scan, chunked hierarchical formulation.
// B=4, T=4096, D=1024. x[b][t][3*1024]: [inp_raw | input_gate_raw | output_gate_raw].
// Recurrence: h_t = a_t*h_{t-1} + b_t, a_t = 1-sigmoid(xg), b_t = tanh(xi)*sigmoid(xg),
// h_{-1} = carry. y_t = tanh(h_t)*sigmoid(xo). Outputs: h_last (4096 floats) then y.
//
// CHUNKS=512 (CLEN=8): 2048 blocks per sweep kernel -> 8 waves/SIMD grid-provided
// (vs 2 at CHUNKS=128), full unroll + up-front load burst for memory-level parallelism.
// The chunk-aggregate scan is itself chunked (SUBC=8, SUPERS=64) so the serial
// middle stage is only 64 steps on 16 blocks; the 8-step stages run on 1024 blocks.

#define B_SZ 4
#define T_LEN 4096
#define DH 1024
#define ROW4 (3 * DH / 4)       // 768 float4 per (b,t) row
#define CHUNKS 512
#define CLEN (T_LEN / CHUNKS)   // 8 timesteps per chunk
#define SUBC 8
#define SUPERS (CHUNKS / SUBC)  // 64 super-chunks of 8 chunks

// native clang vector for nontemporal builtins (HIP float4 is a class, not accepted)
typedef float vf4 __attribute__((ext_vector_type(4)));

__device__ __forceinline__ float fsig(float v) {
    // sigmoid(v) = 1/(1+e^-v)
    return __builtin_amdgcn_rcpf(1.0f + __expf(-v));
}
__device__ __forceinline__ float ftanh(float v) {
    // tanh(v) = 1 - 2/(e^{2v}+1); saturates cleanly
    return 1.0f - 2.0f * __builtin_amdgcn_rcpf(__expf(2.0f * v) + 1.0f);
}

__device__ __forceinline__ void step_ab(float xi, float xg, float& A, float& Bv) {
    const float ig = fsig(xg);
    const float a = 1.f - ig;
    A *= a;
    Bv = a * Bv + ftanh(xi) * ig;
}

// Pass 1: per-chunk aggregates (A = prod a_t, B = local scan with h_in = 0).
// One float4 lane per 4 d-channels; grid (CHUNKS, B). All 16 loads issued up front.
__global__ __launch_bounds__(256) void glru_pass1(const float* __restrict__ x,
                                                  float4* __restrict__ Aag,
                                                  float4* __restrict__ Bag) {
    const int c = blockIdx.x;
    const int b = blockIdx.y;
    const int d4 = threadIdx.x;  // 0..255 -> d = 4*d4..4*d4+3
    const float4* base = (const float4*)x + (size_t)(b * T_LEN + c * CLEN) * ROW4;

    float4 vi[CLEN], vg[CLEN];
    #pragma unroll
    for (int t = 0; t < CLEN; ++t) {
        vi[t] = base[(size_t)t * ROW4 + d4];
        vg[t] = base[(size_t)t * ROW4 + 256 + d4];
    }

    float4 A = make_float4(1.f, 1.f, 1.f, 1.f);
    float4 Bv = make_float4(0.f, 0.f, 0.f, 0.f);
    #pragma unroll
    for (int t = 0; t < CLEN; ++t) {
        step_ab(vi[t].x, vg[t].x, A.x, Bv.x);
        step_ab(vi[t].y, vg[t].y, A.y, Bv.y);
        step_ab(vi[t].z, vg[t].z, A.z, Bv.z);
        step_ab(vi[t].w, vg[t].w, A.w, Bv.w);
    }
    const int o = (b * CHUNKS + c) * 256 + d4;
    Aag[o] = A;
    Bag[o] = Bv;
}

// Pass 2a: reduce SUBC=8 chunk aggregates -> super-aggregate. Full-GPU, coalesced.
// thread id: [b(2) | super(6) | d(10)] so consecutive threads hit consecutive d.
__global__ __launch_bounds__(256) void glru_p2a(const float* __restrict__ Aag,
                                                const float* __restrict__ Bag,
                                                float* __restrict__ Asup,
                                                float* __restrict__ Bsup) {
    const int tid = blockIdx.x * 256 + threadIdx.x;  // 0..262143
    const int d = tid & (DH - 1);
    const int su = (tid >> 10) & (SUPERS - 1);
    const int b = tid >> 16;

    float As = 1.f, Bs = 0.f;
    #pragma unroll
    for (int j = 0; j < SUBC; ++j) {
        const size_t o = ((size_t)(b * CHUNKS + su * SUBC + j) << 10) + d;
        const float a = Aag[o];
        As *= a;
        Bs = a * Bs + Bag[o];
    }
    const int so = (b * SUPERS + su) * DH + d;
    Asup[so] = As;
    Bsup[so] = Bs;
}

// Pass 2b: serial scan across SUPERS=64 super-aggregates per (b,d) chain.
// 4096 threads; emits hsup (h at each super boundary) and h_last (output 0).
__global__ __launch_bounds__(256) void glru_p2b(const float* __restrict__ Asup,
                                                const float* __restrict__ Bsup,
                                                const float* __restrict__ carry,
                                                float* __restrict__ hsup,
                                                float* __restrict__ hlast) {
    const int idx = blockIdx.x * 256 + threadIdx.x;  // 0..4095
    const int b = idx >> 10;
    const int d = idx & (DH - 1);
    float h = carry[idx];
    #pragma unroll 8
    for (int s = 0; s < SUPERS; ++s) {
        const int o = (b * SUPERS + s) * DH + d;
        hsup[o] = h;
        h = Asup[o] * h + Bsup[o];
    }
    hlast[idx] = h;
}

// Pass 2c: expand within each super-chunk: emit h_init per chunk. Full-GPU, coalesced.
__global__ __launch_bounds__(256) void glru_p2c(const float* __restrict__ Aag,
                                                const float* __restrict__ Bag,
                                                const float* __restrict__ hsup,
                                                float* __restrict__ hinit) {
    const int tid = blockIdx.x * 256 + threadIdx.x;
    const int d = tid & (DH - 1);
    const int su = (tid >> 10) & (SUPERS - 1);
    const int b = tid >> 16;

    float h = hsup[(b * SUPERS + su) * DH + d];
    #pragma unroll
    for (int j = 0; j < SUBC; ++j) {
        const size_t o = ((size_t)(b * CHUNKS + su * SUBC + j) << 10) + d;
        hinit[o] = h;
        h = Aag[o] * h + Bag[o];
    }
}

// Pass 3: re-read x, run recurrence from h_init, write y (non-temporal: never re-read).
__global__ __launch_bounds__(256) void glru_pass3(const float* __restrict__ x,
                                                  const float4* __restrict__ hinit,
                                                  float4* __restrict__ y) {
    const int c = blockIdx.x;
    const int b = blockIdx.y;
    const int d4 = threadIdx.x;
    const float4* base = (const float4*)x + (size_t)(b * T_LEN + c * CLEN) * ROW4;
    float4* yb = y + (size_t)(b * T_LEN + c * CLEN) * 256;

    float4 vi[CLEN], vg[CLEN];
    #pragma unroll
    for (int t = 0; t < CLEN; ++t) {
        vi[t] = base[(size_t)t * ROW4 + d4];
        vg[t] = base[(size_t)t * ROW4 + 256 + d4];
    }
    float4 h = hinit[(b * CHUNKS + c) * 256 + d4];

    #pragma unroll
    for (int t = 0; t < CLEN; ++t) {
        const float4 vo = base[(size_t)t * ROW4 + 512 + d4];
        float4 out;
        {
            float ig = fsig(vg[t].x); float a = 1.f - ig;
            h.x = a * h.x + ftanh(vi[t].x) * ig;
            out.x = ftanh(h.x) * fsig(vo.x);
        }
        {
            float ig = fsig(vg[t].y); float a = 1.f - ig;
            h.y = a * h.y + ftanh(vi[t].y) * ig;
            out.y = ftanh(h.y) * fsig(vo.y);
        }
        {
            float ig = fsig(vg[t].z); float a = 1.f - ig;
            h.z = a * h.z + ftanh(vi[t].z) * ig;
            out.z = ftanh(h.z) * fsig(vo.z);
        }
        {
            float ig = fsig(vg[t].w); float a = 1.f - ig;
            h.w = a * h.w + ftanh(vi[t].w) * ig;
            out.w = ftanh(h.w) * fsig(vo.w);
        }
        // native-vector nontemporal store (HIP float4 not accepted by the builtin)
        vf4 outv;
        outv.x = out.x; outv.y = out.y; outv.z = out.z; outv.w = out.w;
        __builtin_nontemporal_store(outv, (vf4*)&yb[(size_t)t * 256 + d4]);
    }
}

extern "C" void kernel_launch(void* const* d_in, const int* in_sizes, int n_in,
                              void* d_out, int out_size, void* d_ws, size_t ws_size,
                              hipStream_t stream) {
    const float* x = (const float*)d_in[0];      // (4, 4096, 3072) fp32
    const float* carry = (const float*)d_in[1];  // (4, 1024) fp32

    float* hlast = (float*)d_out;                      // output 0: (4,1024)
    float4* y = (float4*)((float*)d_out + B_SZ * DH);  // output 1: (4,4096,1024)

    // workspace: Aag/Bag/hinit = 3 * 8 MB, Asup/Bsup/hsup = 3 * 1 MB  (~27 MB)
    float* Aag = (float*)d_ws;
    float* Bag = Aag + (size_t)B_SZ * CHUNKS * DH;
    float* hinit = Bag + (size_t)B_SZ * CHUNKS * DH;
    float* Asup = hinit + (size_t)B_SZ * CHUNKS * DH;
    float* Bsup = Asup + (size_t)B_SZ * SUPERS * DH;
    float* hsup = Bsup + (size_t)B_SZ * SUPERS * DH;

    glru_pass1<<<dim3(CHUNKS, B_SZ), 256, 0, stream>>>(x, (float4*)Aag, (float4*)Bag);
    glru_p2a<<<(B_SZ * SUPERS * DH) / 256, 256, 0, stream>>>(Aag, Bag, Asup, Bsup);
    glru_p2b<<<16, 256, 0, stream>>>(Asup, Bsup, carry, hsup, hlast);
    glru_p2c<<<(B_SZ * SUPERS * DH) / 256, 256, 0, stream>>>(Aag, Bag, hsup, hinit);
    glru_pass3<<<dim3(CHUNKS, B_SZ), 256, 0, stream>>>(x, (const float4*)hinit, y);
}